// Round 1
// baseline (34.695 us; speedup 1.0000x reference)
//
#include <hip/hip_runtime.h>

// Problem constants (HierarchicalIntentClassifier: B=8192, D=768, E=8, K=32)
#define BB 8192
#define DD 768
#define EE 8
#define KK 32

typedef short    short8   __attribute__((ext_vector_type(8)));
typedef float    f32x4    __attribute__((ext_vector_type(4)));
typedef unsigned short us4 __attribute__((ext_vector_type(4)));

// RNE float -> bf16 bits (finite inputs; no NaN path needed)
__device__ __forceinline__ unsigned short f2bf(float f) {
  unsigned int u = __float_as_uint(f);
  u = (u + 0x7fffu + ((u >> 16) & 1u)) >> 16;
  return (unsigned short)u;
}

// ---------------------------------------------------------------------------
// Kernel 1: main_out = pooled @ main_W + main_b, fp32 exact (argmax source).
// One wave per row. lane l accumulates d = l, l+64, ... ; butterfly reduce.
// ---------------------------------------------------------------------------
__global__ __launch_bounds__(256) void main_gemv(
    const float* __restrict__ pooled, const float* __restrict__ mW,
    const float* __restrict__ mb, float* __restrict__ main_out) {
  const int w    = threadIdx.x >> 6;
  const int lane = threadIdx.x & 63;
  const int row  = blockIdx.x * 4 + w;
  const float* p = pooled + (size_t)row * DD;

  f32x4 a0 = {0.f, 0.f, 0.f, 0.f};
  f32x4 a1 = {0.f, 0.f, 0.f, 0.f};
#pragma unroll
  for (int i = 0; i < DD / 64; ++i) {
    int d = lane + 64 * i;
    float pv = p[d];
    f32x4 w0 = *(const f32x4*)(mW + d * EE);      // main_W[d][0..3]
    f32x4 w1 = *(const f32x4*)(mW + d * EE + 4);  // main_W[d][4..7]
    a0 += pv * w0;
    a1 += pv * w1;
  }
#pragma unroll
  for (int off = 32; off >= 1; off >>= 1) {
    a0[0] += __shfl_xor(a0[0], off);
    a0[1] += __shfl_xor(a0[1], off);
    a0[2] += __shfl_xor(a0[2], off);
    a0[3] += __shfl_xor(a0[3], off);
    a1[0] += __shfl_xor(a1[0], off);
    a1[1] += __shfl_xor(a1[1], off);
    a1[2] += __shfl_xor(a1[2], off);
    a1[3] += __shfl_xor(a1[3], off);
  }
  if (lane == 0) {
    f32x4 b0 = *(const f32x4*)(mb);
    f32x4 b1 = *(const f32x4*)(mb + 4);
    a0 += b0;
    a1 += b1;
    *(f32x4*)(main_out + (size_t)row * EE)     = a0;
    *(f32x4*)(main_out + (size_t)row * EE + 4) = a1;
  }
}

// ---------------------------------------------------------------------------
// Kernel 2: dense all-expert sub GEMM (bf16 MFMA) + routed select epilogue.
// Block = 512 threads (8 waves), BM = 32 rows, N = E*K = 256 cols.
// Wave w: M-tile (w>>2), 64-col N-slice ((w&3)*64) -> 4 x mfma_16x16x32 accs.
// A (pooled tile) staged fp32->bf16 in LDS; B read from fp32 sub_W (L2-hot).
// argmax re-derived per row from main_out (no workspace needed).
// ---------------------------------------------------------------------------
__global__ __launch_bounds__(512) void sub_mfma(
    const float* __restrict__ pooled, const float* __restrict__ sub_W,
    const float* __restrict__ sub_b, const int* __restrict__ sub_sizes,
    const float* __restrict__ main_out, float* __restrict__ sub_out) {
  // 776 = 768 + 8 shorts pad: row stride 1552 B (16B-aligned, 388 words -> +4
  // banks per row => ~2-way on ds_read_b128, which is free on CDNA4).
  __shared__ short aS[32][776];
  __shared__ int   idxS[32];
  __shared__ int   szS[32];

  const int t    = threadIdx.x;
  const int row0 = blockIdx.x * 32;

  // --- pre-phase: per-row argmax of main_out (first-max wins, matches np) ---
  if (t < 32) {
    const float* mo = main_out + (size_t)(row0 + t) * EE;
    float best = mo[0];
    int bi = 0;
#pragma unroll
    for (int e = 1; e < EE; ++e) {
      float v = mo[e];
      if (v > best) { best = v; bi = e; }
    }
    idxS[t] = bi;
    szS[t]  = sub_sizes[bi];
  }

  // --- staging: 32x768 fp32 tile -> bf16 LDS (fully contiguous global read) ---
  const float* pbase = pooled + (size_t)row0 * DD;
#pragma unroll
  for (int i = 0; i < 12; ++i) {
    int f  = t + 512 * i;        // float4 index within tile, 0..6143
    int r  = f / 192;            // row 0..31  (192 float4 per row)
    int c4 = f - r * 192;
    f32x4 v = *(const f32x4*)(pbase + (size_t)f * 4);
    us4 u;
    u[0] = f2bf(v[0]); u[1] = f2bf(v[1]); u[2] = f2bf(v[2]); u[3] = f2bf(v[3]);
    *(us4*)&aS[r][c4 * 4] = u;
  }
  __syncthreads();

  // --- K-loop ---
  const int w  = t >> 6, l = t & 63;
  const int mt = w >> 2;            // 0..1 : 16-row M-tile
  const int ns = (w & 3) * 64;      // N-slice base col
  const int lc = l & 15, hi = l >> 4;
  const int arow = mt * 16 + lc;

  f32x4 acc[4] = {};

  for (int ks = 0; ks < DD / 32; ++ks) {
    short8 af = *(const short8*)&aS[arow][ks * 32 + hi * 8];
#pragma unroll
    for (int n = 0; n < 4; ++n) {
      const int c  = ns + n * 16 + lc;   // global col 0..255
      const int e  = c >> 5;             // expert
      const int kk = c & 31;             // col within expert
      const int d0 = ks * 32 + hi * 8;   // same (hi,j)->k map as the A frag
      const float* bp = sub_W + ((size_t)e * (DD * KK) + (size_t)d0 * KK + kk);
      short8 bf;
#pragma unroll
      for (int j = 0; j < 8; ++j) bf[j] = (short)f2bf(bp[(size_t)j * KK]);
      acc[n] = __builtin_amdgcn_mfma_f32_16x16x32_bf16(af, bf, acc[n], 0, 0, 0);
    }
  }

  // --- epilogue: routed select + bias + size mask; each (row,k) written once ---
#pragma unroll
  for (int n = 0; n < 4; ++n) {
    const int c = ns + n * 16 + lc;
    const int e = c >> 5;
    const int k = c & 31;
    const float bias = sub_b[e * KK + k];
#pragma unroll
    for (int q = 0; q < 4; ++q) {
      const int rl = mt * 16 + hi * 4 + q;   // C/D: col = l&15, row = (l>>4)*4+q
      if (idxS[rl] == e) {
        float v = acc[n][q] + bias;
        if (k >= szS[rl]) v = 0.f;
        sub_out[(size_t)(row0 + rl) * KK + k] = v;
      }
    }
  }
}

// ---------------------------------------------------------------------------
extern "C" void kernel_launch(void* const* d_in, const int* in_sizes, int n_in,
                              void* d_out, int out_size, void* d_ws, size_t ws_size,
                              hipStream_t stream) {
  const float* pooled   = (const float*)d_in[0];
  const float* main_W   = (const float*)d_in[1];
  const float* main_b   = (const float*)d_in[2];
  const float* sub_W    = (const float*)d_in[3];
  const float* sub_b    = (const float*)d_in[4];
  const int*   sub_size = (const int*)d_in[5];

  float* main_out = (float*)d_out;                       // [B, E]
  float* sub_out  = (float*)d_out + (size_t)BB * EE;     // [B, K]

  main_gemv<<<BB / 4, 256, 0, stream>>>(pooled, main_W, main_b, main_out);
  sub_mfma<<<BB / 32, 512, 0, stream>>>(pooled, sub_W, sub_b, sub_size,
                                        main_out, sub_out);
}

// Round 2
// 34.244 us; speedup vs baseline: 1.0132x; 1.0132x over previous
//
#include <hip/hip_runtime.h>

// Problem constants (HierarchicalIntentClassifier: B=8192, D=768, E=8, K=32)
#define BB 8192
#define DD 768
#define EE 8
#define KK 32

typedef short    short8 __attribute__((ext_vector_type(8)));
typedef float    f32x4  __attribute__((ext_vector_type(4)));
typedef float    f32x8  __attribute__((ext_vector_type(8)));
typedef unsigned short us4 __attribute__((ext_vector_type(4)));

// RNE float -> bf16 bits (finite inputs; no NaN path needed)
__device__ __forceinline__ unsigned short f2bf(float f) {
  unsigned int u = __float_as_uint(f);
  u = (u + 0x7fffu + ((u >> 16) & 1u)) >> 16;
  return (unsigned short)u;
}

// ---------------------------------------------------------------------------
// Pack kernel: sub_W [E][D][K] fp32  ->  Bp [E][K][D] bf16 in d_ws.
// One thread per 8 d's: 8 strided scalar reads, one coalesced short8 write.
// Total 24576 threads; ~0.8 MB read, 0.4 MB write — trivial.
// ---------------------------------------------------------------------------
__global__ __launch_bounds__(256) void pack_w(const float* __restrict__ sw,
                                              short* __restrict__ bp) {
  const int t  = blockIdx.x * 256 + threadIdx.x;   // 0 .. E*K*D/8-1 (24575)
  const int d0 = (t % (DD / 8)) * 8;
  const int ek = t / (DD / 8);                     // e*K + k
  const int e  = ek >> 5;
  const int k  = ek & 31;
  const float* src = sw + ((size_t)e * DD + d0) * KK + k;
  short8 v;
#pragma unroll
  for (int j = 0; j < 8; ++j) v[j] = (short)f2bf(src[(size_t)j * KK]);
  *(short8*)(bp + (size_t)ek * DD + d0) = v;
}

// ---------------------------------------------------------------------------
// Fused kernel: 512 threads (8 waves), 32 rows per block.
// Phase 1: each wave computes fp32 main logits for 4 rows (exact argmax
//          source), stashing pooled as bf16 into LDS along the way; lane 0
//          finishes +bias, writes main_out, and does the argmax inline.
// Phase 2: dense all-expert MFMA; wave w owns expert w (cols 32w..32w+31),
//          B-fragments are single short8 loads from the packed Bp.
// Epilogue: routed select + bias + size mask; each (row,k) written once.
// ---------------------------------------------------------------------------
__global__ __launch_bounds__(512) void fused(
    const float* __restrict__ pooled, const float* __restrict__ mW,
    const float* __restrict__ mb, const short* __restrict__ Bp,
    const float* __restrict__ sub_b, const int* __restrict__ sub_sizes,
    float* __restrict__ main_out, float* __restrict__ sub_out) {
  // 776 = 768 + 8 shorts pad: row stride 1552 B => ~2-4-way on ds_read_b128
  // (2-way is free on CDNA4), instead of 16-way at stride 768.
  __shared__ short aS[32][776];
  __shared__ int   idxS[32];
  __shared__ int   szS[32];

  const int t    = threadIdx.x;
  const int w    = t >> 6;
  const int lane = t & 63;
  const int row0 = blockIdx.x * 32;

  // ---- Phase 1: main GEMV (fp32) + bf16 stash ----
  f32x8 acc[4] = {};   // 4 rows per wave
#pragma unroll
  for (int i = 0; i < 3; ++i) {
    const int d = (i * 64 + lane) * 4;
    // main_W rows d..d+3 (each [8] fp32). L2/L1-hot (24 KB total).
    f32x8 W0 = *(const f32x8*)(mW + (size_t)(d + 0) * EE);
    f32x8 W1 = *(const f32x8*)(mW + (size_t)(d + 1) * EE);
    f32x8 W2 = *(const f32x8*)(mW + (size_t)(d + 2) * EE);
    f32x8 W3 = *(const f32x8*)(mW + (size_t)(d + 3) * EE);
#pragma unroll
    for (int rr = 0; rr < 4; ++rr) {
      const int r = w * 4 + rr;
      f32x4 v = *(const f32x4*)(pooled + (size_t)(row0 + r) * DD + d);
      us4 u;
      u[0] = f2bf(v[0]); u[1] = f2bf(v[1]); u[2] = f2bf(v[2]); u[3] = f2bf(v[3]);
      *(us4*)&aS[r][d] = u;
      acc[rr] += v[0] * W0;
      acc[rr] += v[1] * W1;
      acc[rr] += v[2] * W2;
      acc[rr] += v[3] * W3;
    }
  }
#pragma unroll
  for (int rr = 0; rr < 4; ++rr) {
#pragma unroll
    for (int off = 32; off >= 1; off >>= 1) {
#pragma unroll
      for (int j = 0; j < 8; ++j) acc[rr][j] += __shfl_xor(acc[rr][j], off);
    }
    if (lane == 0) {
      const int r = w * 4 + rr;
      f32x8 res = acc[rr] + *(const f32x8*)mb;
      *(f32x8*)(main_out + (size_t)(row0 + r) * EE) = res;
      float best = res[0];
      int   bi   = 0;
#pragma unroll
      for (int e = 1; e < EE; ++e) {
        if (res[e] > best) { best = res[e]; bi = e; }
      }
      idxS[r] = bi;
      szS[r]  = sub_sizes[bi];
    }
  }
  __syncthreads();

  // ---- Phase 2: MFMA K-loop. Wave w = expert w, cols k = n*16 + (lane&15).
  const int lc = lane & 15, hi = lane >> 4;
  const short* bb  = Bp + (size_t)w * KK * DD + (size_t)hi * 8;
  const short* bp0 = bb + (size_t)(lc) * DD;         // k = lc
  const short* bp1 = bb + (size_t)(16 + lc) * DD;    // k = 16 + lc
  f32x4 a2[2][2] = {};

  for (int ks = 0; ks < DD / 32; ++ks) {
    const int d0 = ks * 32 + hi * 8;
    short8 b0 = *(const short8*)(bp0 + ks * 32);
    short8 b1 = *(const short8*)(bp1 + ks * 32);
    short8 a0 = *(const short8*)&aS[lc][d0];
    short8 a1 = *(const short8*)&aS[16 + lc][d0];
    a2[0][0] = __builtin_amdgcn_mfma_f32_16x16x32_bf16(a0, b0, a2[0][0], 0, 0, 0);
    a2[0][1] = __builtin_amdgcn_mfma_f32_16x16x32_bf16(a0, b1, a2[0][1], 0, 0, 0);
    a2[1][0] = __builtin_amdgcn_mfma_f32_16x16x32_bf16(a1, b0, a2[1][0], 0, 0, 0);
    a2[1][1] = __builtin_amdgcn_mfma_f32_16x16x32_bf16(a1, b1, a2[1][1], 0, 0, 0);
  }

  // ---- Epilogue: routed select. idxS/szS were written before the barrier.
#pragma unroll
  for (int n = 0; n < 2; ++n) {
    const int k = n * 16 + lc;
    const float bias = sub_b[w * KK + k];
#pragma unroll
    for (int mt = 0; mt < 2; ++mt) {
#pragma unroll
      for (int q = 0; q < 4; ++q) {
        const int rl = mt * 16 + hi * 4 + q;   // C/D: col=lane&15, row=(l>>4)*4+q
        if (idxS[rl] == w) {
          float v = a2[mt][n][q] + bias;
          if (k >= szS[rl]) v = 0.f;
          sub_out[(size_t)(row0 + rl) * KK + k] = v;
        }
      }
    }
  }
}

// ---------------------------------------------------------------------------
extern "C" void kernel_launch(void* const* d_in, const int* in_sizes, int n_in,
                              void* d_out, int out_size, void* d_ws, size_t ws_size,
                              hipStream_t stream) {
  const float* pooled   = (const float*)d_in[0];
  const float* main_W   = (const float*)d_in[1];
  const float* main_b   = (const float*)d_in[2];
  const float* sub_W    = (const float*)d_in[3];
  const float* sub_b    = (const float*)d_in[4];
  const int*   sub_size = (const int*)d_in[5];

  float* main_out = (float*)d_out;                    // [B, E]
  float* sub_out  = (float*)d_out + (size_t)BB * EE;  // [B, K]
  short* Bp       = (short*)d_ws;                     // [E][K][D] bf16, 384 KB

  pack_w<<<(EE * KK * DD / 8) / 256, 256, 0, stream>>>(sub_W, Bp);
  fused<<<BB / 32, 512, 0, stream>>>(pooled, main_W, main_b, Bp, sub_b,
                                     sub_size, main_out, sub_out);
}